// Round 4
// baseline (185.588 us; speedup 1.0000x reference)
//
#include <hip/hip_runtime.h>
#include <hip/hip_bf16.h>
#include <cmath>

typedef _Float16 half_t;
typedef half_t half4 __attribute__((ext_vector_type(4)));
typedef half_t half8 __attribute__((ext_vector_type(8)));
typedef float f32x4 __attribute__((ext_vector_type(4)));

#define N_HEADS 16
#define HD      64
#define T_SEQ   2048
#define B_SZ    2
#define C_DIM   1024
#define M_ROWS  (B_SZ * T_SEQ)   /* 4096 */
#define N_QKV   (3 * C_DIM)      /* 3072 */
#define QSCALE  0.18033688f      /* 0.125 * log2(e), folded into Q at rope */

__device__ inline void load_lds16(const half_t* g, half_t* l) {
  __builtin_amdgcn_global_load_lds(
      (const __attribute__((address_space(1))) void*)g,
      (__attribute__((address_space(3))) void*)l, 16, 0, 0);
}

// ---- fused prep: x->f16 (0..4095), w_attn^T (..4863), w_proj^T (..5119),
// ---- rope cos/sin table (5120..5375): tbl[t][j] = {cos,sin}(t*10000^(-j/32))
__global__ __launch_bounds__(256) void k_prep(const float* __restrict__ x,
                                              half_t* __restrict__ xb,
                                              const float* __restrict__ wa,
                                              half_t* __restrict__ wT,
                                              const float* __restrict__ wp,
                                              half_t* __restrict__ wpT,
                                              float2* __restrict__ tbl) {
  __shared__ float tile[64][65];
  int bid = blockIdx.x, tid = threadIdx.x;
  if (bid < 4096) {
    int i = (bid * 256 + tid) * 4;
    float4 v = *(const float4*)(x + i);
    half_t o[4] = {(half_t)v.x, (half_t)v.y, (half_t)v.z, (half_t)v.w};
    *(ulong1*)(xb + i) = *(ulong1*)o;
    return;
  }
  if (bid >= 5120) {                       // rope table: 65536 entries
    int idx = (bid - 5120) * 256 + tid;
    int t = idx >> 5, j = idx & 31;
    float inv = exp2f(-(float)j * (13.287712379549449f / 32.0f));
    float s, c;
    sincosf((float)t * inv, &s, &c);
    tbl[idx] = make_float2(c, s);
    return;
  }
  const float* in; half_t* out; int K, N, id;
  if (bid < 4864) { id = bid - 4096; in = wa; out = wT;  K = 1024; N = 3072; }
  else            { id = bid - 4864; in = wp; out = wpT; K = 1024; N = 1024; }
  int n0 = (id % (N / 64)) * 64, k0 = (id / (N / 64)) * 64;
  int tx = tid & 63, ty = tid >> 6;
  #pragma unroll
  for (int i = 0; i < 64; i += 4)
    tile[ty + i][tx] = in[(size_t)(k0 + ty + i) * N + n0 + tx];
  __syncthreads();
  #pragma unroll
  for (int i = 0; i < 64; i += 4) {
    int r = ty + i;
    out[(size_t)(n0 + r) * K + k0 + tx] = (half_t)tile[tx][r];
  }
}

// ------------- GEMM: C = A(f16,[M][K]) * Bt(f16,[N][K])^T + bias, OT out ----
// 128xTN tile, BK=64, global_load_lds width-16 into XOR-swizzled LDS.
template <typename OT, int TN>
__global__ __launch_bounds__(256) void k_gemm(const half_t* __restrict__ A,
                                              const half_t* __restrict__ Bt,
                                              const float* __restrict__ bias,
                                              OT* __restrict__ C,
                                              int M, int N, int K) {
  constexpr int NI = TN / 32;          // n-fragments per wave
  __shared__ half_t As[128 * 64];
  __shared__ half_t Bs[TN * 64];
  int tid = threadIdx.x;
  int wave = tid >> 6, lane = tid & 63;
  int lane15 = lane & 15, quad = lane >> 4;
  int wm = (wave >> 1) * 64, wn = (wave & 1) * (TN / 2);
  int bm0 = blockIdx.y * 128, bn0 = blockIdx.x * TN;
  f32x4 acc[4][NI] = {};

  for (int kb = 0; kb < K; kb += 64) {
    const half_t* Ag = A + (size_t)bm0 * K + kb;
    const half_t* Bg = Bt + (size_t)bn0 * K + kb;
    __syncthreads();
    #pragma unroll
    for (int p = 0; p < 4; p++) {
      int fc = wave * 4 * 64 + p * 64 + lane;
      int r = fc >> 3, c = (fc & 7) ^ (r & 7);
      load_lds16(Ag + (size_t)r * K + c * 8, As + (wave * 4 + p) * 512);
    }
    #pragma unroll
    for (int p = 0; p < NI; p++) {
      int fc = wave * NI * 64 + p * 64 + lane;
      int r = fc >> 3, c = (fc & 7) ^ (r & 7);
      load_lds16(Bg + (size_t)r * K + c * 8, Bs + (wave * NI + p) * 512);
    }
    __syncthreads();
    #pragma unroll
    for (int ks = 0; ks < 2; ks++) {
      half8 af[4], bf[NI];
      #pragma unroll
      for (int i = 0; i < 4; i++) {
        int Ra = wm + i * 16 + lane15;
        af[i] = *(const half8*)(As + Ra * 64 + ((ks * 4 + quad) ^ (Ra & 7)) * 8);
      }
      #pragma unroll
      for (int i = 0; i < NI; i++) {
        int Rb = wn + i * 16 + lane15;
        bf[i] = *(const half8*)(Bs + Rb * 64 + ((ks * 4 + quad) ^ (Rb & 7)) * 8);
      }
      #pragma unroll
      for (int mi = 0; mi < 4; mi++)
        #pragma unroll
        for (int ni = 0; ni < NI; ni++)
          acc[mi][ni] = __builtin_amdgcn_mfma_f32_16x16x32_f16(af[mi], bf[ni], acc[mi][ni], 0, 0, 0);
    }
  }
  #pragma unroll
  for (int mi = 0; mi < 4; mi++)
    #pragma unroll
    for (int ni = 0; ni < NI; ni++) {
      int n = bn0 + wn + ni * 16 + lane15;
      float bv = bias[n];
      int mrow = bm0 + wm + mi * 16 + quad * 4;
      #pragma unroll
      for (int r = 0; r < 4; r++)
        C[(size_t)(mrow + r) * N + n] = (OT)(acc[mi][ni][r] + bv);
    }
}

// ------------- fused QKV GEMM + bias + RoPE + reorg -------------
// 128x128 tile over [M=4096][N=3072]; each 128-wide N tile lies entirely in
// one of {Q,K,V} (1024 % 128 == 0). Epilogue:
//   Q/K tiles: rope pairs (d, d+32) are acc[mi][p] / acc[mi][p+2] of the SAME
//     thread (d = ni*16+lane15). Rotation in f32 registers via tbl[t][j],
//     then direct store to Q/K [bh][t][d] (Q pre-scaled by QSCALE).
//   V tiles: acc -> LDS [128][130] transpose -> blocked store
//     Vt[bh][t/64][d][t%64] (contiguous 8KB per kv tile for flash staging).
// Deletes the k_rope kernel (50MB HBM round-trip + 2M sincosf).
__global__ __launch_bounds__(256) void k_gemm_qkv(const half_t* __restrict__ A,
                                                  const half_t* __restrict__ Bt,
                                                  const float* __restrict__ bias,
                                                  const float2* __restrict__ tbl,
                                                  half_t* __restrict__ Qo,
                                                  half_t* __restrict__ Ko,
                                                  half_t* __restrict__ Vo) {
  __shared__ half_t smem[16640];           // As 8192 | Bs 8192 ; V: vt[128][130]
  half_t* As = smem;
  half_t* Bs = smem + 8192;
  int tid = threadIdx.x;
  int wave = tid >> 6, lane = tid & 63;
  int lane15 = lane & 15, quad = lane >> 4;
  int wm = (wave >> 1) * 64, wn = (wave & 1) * 64;
  int bm0 = blockIdx.y * 128, bn0 = blockIdx.x * 128;
  f32x4 acc[4][4] = {};

  for (int kb = 0; kb < C_DIM; kb += 64) {
    const half_t* Ag = A + (size_t)bm0 * C_DIM + kb;
    const half_t* Bg = Bt + (size_t)bn0 * C_DIM + kb;
    __syncthreads();
    #pragma unroll
    for (int p = 0; p < 4; p++) {
      int fc = wave * 4 * 64 + p * 64 + lane;
      int r = fc >> 3, c = (fc & 7) ^ (r & 7);
      load_lds16(Ag + (size_t)r * C_DIM + c * 8, As + (wave * 4 + p) * 512);
    }
    #pragma unroll
    for (int p = 0; p < 4; p++) {
      int fc = wave * 4 * 64 + p * 64 + lane;
      int r = fc >> 3, c = (fc & 7) ^ (r & 7);
      load_lds16(Bg + (size_t)r * C_DIM + c * 8, Bs + (wave * 4 + p) * 512);
    }
    __syncthreads();
    #pragma unroll
    for (int ks = 0; ks < 2; ks++) {
      half8 af[4], bf[4];
      #pragma unroll
      for (int i = 0; i < 4; i++) {
        int Ra = wm + i * 16 + lane15;
        af[i] = *(const half8*)(As + Ra * 64 + ((ks * 4 + quad) ^ (Ra & 7)) * 8);
      }
      #pragma unroll
      for (int i = 0; i < 4; i++) {
        int Rb = wn + i * 16 + lane15;
        bf[i] = *(const half8*)(Bs + Rb * 64 + ((ks * 4 + quad) ^ (Rb & 7)) * 8);
      }
      #pragma unroll
      for (int mi = 0; mi < 4; mi++)
        #pragma unroll
        for (int ni = 0; ni < 4; ni++)
          acc[mi][ni] = __builtin_amdgcn_mfma_f32_16x16x32_f16(af[mi], bf[ni], acc[mi][ni], 0, 0, 0);
    }
  }
  // bias (b_attn) BEFORE rope, matching reference
  #pragma unroll
  for (int ni = 0; ni < 4; ni++) {
    float bv = bias[bn0 + wn + ni * 16 + lane15];
    #pragma unroll
    for (int mi = 0; mi < 4; mi++)
      #pragma unroll
      for (int r = 0; r < 4; r++) acc[mi][ni][r] += bv;
  }

  int third = bn0 >> 10;                   // 0=Q, 1=K, 2=V (block-uniform)
  if (third < 2) {
    half_t* Ob = (third == 0) ? Qo : Ko;
    int h = ((bn0 & 1023) + wn) >> 6;      // head for this wave's columns
    #pragma unroll
    for (int mi = 0; mi < 4; mi++) {
      int mrow = bm0 + wm + mi * 16 + quad * 4;
      int bq = mrow >> 11, tq = mrow & 2047;
      half_t* outp = Ob + ((size_t)(bq * 16 + h) * T_SEQ + tq) * HD;
      #pragma unroll
      for (int p = 0; p < 2; p++) {        // pair (d=j, d=j+32), j = p*16+lane15
        int j = p * 16 + lane15;
        #pragma unroll
        for (int r = 0; r < 4; r++) {
          float2 cs = tbl[(tq + r) * 32 + j];
          float a1 = acc[mi][p][r], a2 = acc[mi][p + 2][r];
          float o1 = a1 * cs.x - a2 * cs.y;
          float o2 = a1 * cs.y + a2 * cs.x;
          if (third == 0) { o1 *= QSCALE; o2 *= QSCALE; }
          outp[r * HD + j]      = (half_t)o1;
          outp[r * HD + j + 32] = (half_t)o2;
        }
      }
    }
  } else {
    // V: transpose through LDS, store blocked [bh][t/64][d][t%64]
    __syncthreads();                       // all waves done reading As/Bs
    #pragma unroll
    for (int mi = 0; mi < 4; mi++)
      #pragma unroll
      for (int ni = 0; ni < 4; ni++) {
        int tl = wm + mi * 16 + quad * 4, nl = wn + ni * 16 + lane15;
        #pragma unroll
        for (int r = 0; r < 4; r++)
          smem[(tl + r) * 130 + nl] = (half_t)acc[mi][ni][r];
      }
    __syncthreads();
    int hV = (bn0 - 2048) >> 6;
    int bq = bm0 >> 11, tq0 = bm0 & 2047;
    int c8 = (tid & 7) * 8;                // 8 lanes cover one 128B d-row
    #pragma unroll
    for (int p = 0; p < 8; p++) {
      int gr = p * 32 + (tid >> 3);        // 256 rows: (h2, d, tblk)
      int tb = gr & 1, d = (gr >> 1) & 63, h2 = gr >> 7;
      half8 vv;
      #pragma unroll
      for (int jj = 0; jj < 8; jj++)
        vv[jj] = smem[(tb * 64 + c8 + jj) * 130 + h2 * 64 + d];
      *(half8*)(Vo + ((size_t)((bq * 16 + hV + h2) * 32 + (tq0 >> 6) + tb) * 64 + d) * 64 + c8) = vv;
    }
  }
}

// ------------- causal flash v3: 128-q tiles, kv-split-2, 16 waves -------------
// 16 waves: waves 0-7 = group 0 (even kv tiles), 8-15 = group 1 (odd).
// Rounds per 128-q tile = qt+1; block does tiles x and 15-x -> 17 rounds for
// EVERY block. Grid (8,32) = 256 blocks = 1/CU, 16 waves/CU steady, no tail.
// V is kv-tile-blocked [bh][tile][d][64]: stage reads are contiguous 8KB
// (R3's [d][t] layout read 64 lines at 4KB stride -> L2 set aliasing).
template <bool DIAG>
__device__ __forceinline__ void tile_mfma(const half_t* __restrict__ Kt,
                                          const half_t* __restrict__ Vt,
                                          half8 bq0, half8 bq1,
                                          f32x4 (&ot)[4], float& l,
                                          int lane15, int quad, int qloc) {
  f32x4 sacc[4];
  #pragma unroll
  for (int s = 0; s < 4; s++) {
    int R_ = s * 16 + lane15;
    half8 ak0 = *(const half8*)(Kt + R_ * 64 + ((quad) ^ (R_ & 7)) * 8);
    half8 ak1 = *(const half8*)(Kt + R_ * 64 + ((4 + quad) ^ (R_ & 7)) * 8);
    f32x4 z = {};
    z = __builtin_amdgcn_mfma_f32_16x16x32_f16(ak0, bq0, z, 0, 0, 0);
    sacc[s] = __builtin_amdgcn_mfma_f32_16x16x32_f16(ak1, bq1, z, 0, 0, 0);
  }
  #pragma unroll
  for (int s = 0; s < 4; s++) {
    half4 bp;
    #pragma unroll
    for (int r = 0; r < 4; r++) {
      float sv = sacc[s][r];
      if (DIAG && (s * 16 + quad * 4 + r > qloc)) sv = -1.0e30f;
      float p = exp2f(fminf(sv, 14.0f));
      l += p;
      bp[r] = (half_t)p;
    }
    #pragma unroll
    for (int nm = 0; nm < 4; nm++) {
      int Rv = nm * 16 + lane15;
      half4 av = *(const half4*)(Vt + Rv * 64 +
                                 ((2 * s + (quad >> 1)) ^ (Rv & 7)) * 8 +
                                 (quad & 1) * 4);
      ot[nm] = __builtin_amdgcn_mfma_f32_16x16x16f16(av, bp, ot[nm], 0, 0, 0);
    }
  }
}

// Stage kv tiles {2t, 2t+1} of K and V into buffer bb. 1024 threads, each
// issues 1 K + 1 V load_lds16 (16B): waves 0-7 serve group 0's tile (2t),
// waves 8-15 serve group 1's tile (2t+1). 32KB total per stage.
#define STAGE(bb, t_)                                                          \
  {                                                                            \
    int gS = wave >> 3;                                                        \
    int idx = (wave & 7) * 64 + lane;                                          \
    int rr_ = idx >> 3, cc = (idx & 7) ^ (rr_ & 7);                            \
    int j = 2 * (t_) + gS;                                                     \
    load_lds16(Kb + (size_t)(j * 64 + rr_) * HD + cc * 8,                      \
               &KV[bb][0][gS][0] + idx * 8);                                   \
    load_lds16(Vb + (size_t)j * 4096 + rr_ * 64 + cc * 8,                      \
               &KV[bb][1][gS][0] + idx * 8);                                   \
  }

__device__ __forceinline__ void process_tile(
    int qt, const half_t* __restrict__ Qb, const half_t* __restrict__ Kb,
    const half_t* __restrict__ Vb, half_t* __restrict__ y, int b, int h,
    half_t (&KV)[2][2][2][4096],
    int wave, int lane, int g, int wq, int lane15, int quad) {
  int q0 = qt * 128;
  int qrow = q0 + wq * 16 + lane15;        // this wave's q column (S^T B-op n)
  half8 bq0 = *(const half8*)(Qb + (size_t)qrow * HD + quad * 8);
  half8 bq1 = *(const half8*)(Qb + (size_t)qrow * HD + 32 + quad * 8);
  f32x4 ot[4] = {};                        // O^T: d = nm*16+quad*4+r, q = lane15
  float l = 0.f;
  int R = qt + 1;                          // rounds: group g does kv tile 2r+g
  // hot loop: rounds 0..R-2, both groups unmasked
  for (int r = 0; r < R - 1; r++) {
    __syncthreads();                       // stage(r) DMA drained & visible
    STAGE((r + 1) & 1, r + 1);             // prefetch overlaps compute
    tile_mfma<false>(&KV[r & 1][0][g][0], &KV[r & 1][1][g][0], bq0, bq1, ot, l,
                     lane15, quad, 0);
  }
  // last round (r = R-1): group 0 on tile 2qt (diag for wq<4, auto-full for
  // wq>=4 since qloc>=64>srow); group 1 on tile 2qt+1 (skip wq<4, diag wq>=4)
  __syncthreads();
  {
    int buf = (R - 1) & 1;
    const half_t* Kt = &KV[buf][0][g][0];
    const half_t* Vt = &KV[buf][1][g][0];
    if (g == 0)
      tile_mfma<true>(Kt, Vt, bq0, bq1, ot, l, lane15, quad, wq * 16 + lane15);
    else if (wq >= 4)
      tile_mfma<true>(Kt, Vt, bq0, bq1, ot, l, lane15, quad,
                      (wq - 4) * 16 + lane15);
  }
  // per-wave l: sum the 4 quads holding this q-column
  l += __shfl_xor(l, 16);
  l += __shfl_xor(l, 32);
  // cross-group combine via LDS (reuse KV region, 512*17*4B = 34.8KB <= 64KB)
  __syncthreads();                         // all compute reads of K/V done
  float* cb = (float*)&KV[0][0][0][0];
  int ci = (wq * 64 + lane) * 17;          // stride 17 floats: conflict-free
  if (g == 1) {
    #pragma unroll
    for (int nm = 0; nm < 4; nm++)
      #pragma unroll
      for (int r = 0; r < 4; r++) cb[ci + nm * 4 + r] = ot[nm][r];
    cb[ci + 16] = l;
  }
  __syncthreads();
  if (g == 0) {
    #pragma unroll
    for (int nm = 0; nm < 4; nm++)
      #pragma unroll
      for (int r = 0; r < 4; r++) ot[nm][r] += cb[ci + nm * 4 + r];
    l += cb[ci + 16];
    float invl = 1.0f / l;
    int t = q0 + wq * 16 + lane15;
    half_t* yr = y + (size_t)(b * T_SEQ + t) * C_DIM + h * 64;
    #pragma unroll
    for (int nm = 0; nm < 4; nm++) {
      half4 o4;
      #pragma unroll
      for (int r = 0; r < 4; r++) o4[r] = (half_t)(ot[nm][r] * invl);
      *(half4*)(yr + nm * 16 + quad * 4) = o4;   // 8B store
    }
  }
  __syncthreads();                         // combine region free before restage
}

__global__ __launch_bounds__(1024, 4) void k_flash(const half_t* __restrict__ Qg,
                                                   const half_t* __restrict__ Kg,
                                                   const half_t* __restrict__ Vg,
                                                   half_t* __restrict__ y) {
  __shared__ half_t KV[2][2][2][4096];     // [buf][K/V][grp][64*64]
  int bh = blockIdx.y;
  int b = bh >> 4, h = bh & 15;
  int x = blockIdx.x;                      // 0..7: q-tile pair (x, 15-x)
  int tid = threadIdx.x;
  int wave = tid >> 6, lane = tid & 63;
  int g = wave >> 3, wq = wave & 7;        // kv-parity group, q-warp in group
  int lane15 = lane & 15, quad = lane >> 4;
  const half_t* Qb = Qg + (size_t)bh * T_SEQ * HD;
  const half_t* Kb = Kg + (size_t)bh * T_SEQ * HD;
  const half_t* Vb = Vg + (size_t)bh * HD * T_SEQ;

  int qtA = x, qtB = 15 - x;
  STAGE(0, 0);
  process_tile(qtA, Qb, Kb, Vb, y, b, h, KV, wave, lane, g, wq, lane15, quad);
  STAGE(0, 0);                             // one un-overlapped stage per block
  process_tile(qtB, Qb, Kb, Vb, y, b, h, KV, wave, lane, g, wq, lane15, quad);
  #undef STAGE
}

extern "C" void kernel_launch(void* const* d_in, const int* in_sizes, int n_in,
                              void* d_out, int out_size, void* d_ws, size_t ws_size,
                              hipStream_t stream) {
  const float* x      = (const float*)d_in[0];
  const float* w_attn = (const float*)d_in[1];
  const float* b_attn = (const float*)d_in[2];
  const float* w_proj = (const float*)d_in[3];
  const float* b_proj = (const float*)d_in[4];
  float* out = (float*)d_out;

  char* ws = (char*)d_ws;
  const size_t MB = 1u << 20;
  half_t* xb  = (half_t*)(ws);             // 8 MB  x in f16
  half_t* wT  = (half_t*)(ws + 8 * MB);    // 6 MB  w_attn^T f16 [3072][1024]
  half_t* wpT = (half_t*)(ws + 14 * MB);   // 2 MB  w_proj^T f16 [1024][1024]
  half_t* Q   = (half_t*)(ws + 16 * MB);   // 8 MB  [bh][t][d]  (pre-scaled)
  half_t* Kb  = (half_t*)(ws + 24 * MB);   // 8 MB  [bh][t][d]
  half_t* Vt  = (half_t*)(ws + 32 * MB);   // 8 MB  [bh][t/64][d][t%64] blocked
  half_t* y   = (half_t*)(ws + 40 * MB);   // 8 MB  attn out f16
  float2* tbl = (float2*)(ws + 48 * MB);   // 512KB rope table [2048][32]

  k_prep<<<4096 + 768 + 256 + 256, 256, 0, stream>>>(x, xb, w_attn, wT,
                                                     w_proj, wpT, tbl);
  k_gemm_qkv<<<dim3(N_QKV / 128, M_ROWS / 128), 256, 0, stream>>>(
      xb, wT, b_attn, tbl, Q, Kb, Vt);
  k_flash<<<dim3(8, B_SZ * N_HEADS), 1024, 0, stream>>>(Q, Kb, Vt, y);
  k_gemm<float, 64><<<dim3(C_DIM / 64, M_ROWS / 128), 256, 0, stream>>>(
      y, wpT, b_proj, out, M_ROWS, C_DIM, C_DIM);
}